// Round 1
// baseline (819.399 us; speedup 1.0000x reference)
//
#include <hip/hip_runtime.h>
#include <hip/hip_fp16.h>

#define BB   8
#define NPTS 4096
#define SS   1024
#define KK   128

typedef _Float16 half8 __attribute__((ext_vector_type(8)));
typedef float    f32x4 __attribute__((ext_vector_type(4)));

// ---------------------------------------------------------------------------
// Kernel 1 (fused): blocks [0,8) = FPS (one per cloud); blocks [8,8+4096) = E.
//   E[n][c] = x[n]*W1[0:3][c] + pos[n]*W1[3:6][c]   (query-independent)
//   FPS: 512 threads, 8 pts/thread, bit-exact, 1 barrier/iter.
//   Wave argmax: f32 DPP fmax + ballot/ffs/readlane (index-carrying, cheap);
//   selected coords come from the 64 KB LDS point cache.
//   R3 change: the main loop does ZERO global-memory ops. pos_out/batch_out
//   writes are deferred to an epilogue (winning index per iter recorded in
//   LDS gsel[]), so the compiler's `s_waitcnt vmcnt(0)` before each
//   s_barrier no longer waits on an HBM store-ack every iteration.
// ---------------------------------------------------------------------------
#define FPS_T 512
#define PPT   8

// one DPP fmax step (old preserved on disabled lanes => identity for max)
#define DPP_FMAX(CTRL)                                                                  \
    {                                                                                   \
        unsigned o = (unsigned)__builtin_amdgcn_update_dpp(                             \
            (int)__float_as_uint(m), (int)__float_as_uint(m), CTRL, 0xF, 0xF, false);   \
        m = fmaxf(m, __uint_as_float(o));                                               \
    }

__global__ __launch_bounds__(FPS_T) void fps_e_kernel(const float* __restrict__ pos,
                                                      const int* __restrict__ batch,
                                                      const float* __restrict__ x,
                                                      const float* __restrict__ W1,
                                                      float* __restrict__ E,
                                                      float* __restrict__ pos_out,
                                                      float* __restrict__ batch_out) {
    if (blockIdx.x >= BB) {
        // ---- E part: id over 32768*64, 4096 blocks x 512 threads
        int id = (blockIdx.x - BB) * FPS_T + threadIdx.x;
        int c = id & 63;
        int n = id >> 6;
        float x0 = x[n * 3 + 0], x1 = x[n * 3 + 1], x2 = x[n * 3 + 2];
        float p0 = pos[n * 3 + 0], p1 = pos[n * 3 + 1], p2 = pos[n * 3 + 2];
        float v = x0 * W1[0 * 64 + c] + x1 * W1[1 * 64 + c] + x2 * W1[2 * 64 + c]
                + p0 * W1[3 * 64 + c] + p1 * W1[4 * 64 + c] + p2 * W1[5 * 64 + c];
        E[(size_t)n * 64 + c] = v;
        return;
    }

    // ---- FPS part
    __shared__ __align__(16) float4 Pl[NPTS];                 // 64 KB point cache
    __shared__ __align__(16) unsigned long long wkey[2][8];   // parity-double-buffered
    __shared__ int gsel[SS];                                  // winning index per iter

    int b = blockIdx.x;
    int t = threadIdx.x;
    int w = t >> 6, l = t & 63;
    const float* P = pos + (size_t)b * NPTS * 3;

    // stage all coords into LDS (exact copies)
    for (int i = t; i < NPTS; i += FPS_T) {
        Pl[i] = make_float4(P[i * 3 + 0], P[i * 3 + 1], P[i * 3 + 2], 0.f);
    }
    if (t == 0) gsel[0] = 0;

    // per-thread registers
    float px[PPT], py[PPT], pz[PPT], md[PPT];
    int base = t * PPT;
#pragma unroll
    for (int j = 0; j < PPT; j++) {
        px[j] = P[(base + j) * 3 + 0];
        py[j] = P[(base + j) * 3 + 1];
        pz[j] = P[(base + j) * 3 + 2];
    }
    float c0x = P[0], c0y = P[1], c0z = P[2];
#pragma unroll
    for (int j = 0; j < PPT; j++) {
        float dx = __fsub_rn(px[j], c0x);
        float dy = __fsub_rn(py[j], c0y);
        float dz = __fsub_rn(pz[j], c0z);
        md[j] = __fadd_rn(__fadd_rn(__fmul_rn(dx, dx), __fmul_rn(dy, dy)), __fmul_rn(dz, dz));
    }
    __syncthreads();   // Pl ready

    for (int s = 1; s < SS; s++) {
        // ---- local max over 8 pts (fmax tree; compiler can fuse to max3)
        float lm = fmaxf(fmaxf(fmaxf(md[0], md[1]), fmaxf(md[2], md[3])),
                         fmaxf(fmaxf(md[4], md[5]), fmaxf(md[6], md[7])));
        // smallest j attaining lm
        int jsel = 0x7FFFFFFF;
#pragma unroll
        for (int j = PPT - 1; j >= 0; j--)
            if (md[j] == lm) jsel = base + j;

        // ---- wave max via f32 DPP
        float m = lm;
        DPP_FMAX(0x111)   // row_shr:1
        DPP_FMAX(0x112)   // row_shr:2
        DPP_FMAX(0x114)   // row_shr:4
        DPP_FMAX(0x118)   // row_shr:8
        DPP_FMAX(0x142)   // row_bcast:15
        DPP_FMAX(0x143)   // row_bcast:31
        float wm = __uint_as_float((unsigned)__builtin_amdgcn_readlane(__float_as_uint(m), 63));

        // ---- first lane attaining wm = smallest index (lanes ordered by base)
        unsigned long long mask = __ballot(lm == wm);
        int L = __ffsll((long long)mask) - 1;
        int si = __builtin_amdgcn_readlane(jsel, L);          // wave's argmax index (uniform)

        if (l == 0)
            wkey[s & 1][w] = (((unsigned long long)__float_as_uint(wm)) << 32) | (~(unsigned)si);
        __syncthreads();

        // ---- cross-wave combine (uniform broadcast reads; max key = max d2, tie -> min idx)
        const unsigned long long* wk = wkey[s & 1];
        unsigned long long g0 = wk[0] > wk[1] ? wk[0] : wk[1];
        unsigned long long g1 = wk[2] > wk[3] ? wk[2] : wk[3];
        unsigned long long g2 = wk[4] > wk[5] ? wk[4] : wk[5];
        unsigned long long g3 = wk[6] > wk[7] ? wk[6] : wk[7];
        unsigned long long ga = g0 > g1 ? g0 : g1;
        unsigned long long gb = g2 > g3 ? g2 : g3;
        unsigned long long g = ga > gb ? ga : gb;
        int gi = (int)(~(unsigned)g);

        if (t == 0) gsel[s] = gi;               // LDS only -- no vmcnt on the barrier

        float4 c = Pl[gi];                      // LDS broadcast
#pragma unroll
        for (int j = 0; j < PPT; j++) {
            float dx = __fsub_rn(px[j], c.x);
            float dy = __fsub_rn(py[j], c.y);
            float dz = __fsub_rn(pz[j], c.z);
            float d2 = __fadd_rn(__fadd_rn(__fmul_rn(dx, dx), __fmul_rn(dy, dy)), __fmul_rn(dz, dz));
            md[j] = fminf(md[j], d2);
        }
    }

    // ---- epilogue: all global writes happen once, off the critical loop
    __syncthreads();   // gsel visible to all threads
    for (int i = t; i < SS; i += FPS_T) {
        int gi = gsel[i];
        float4 c = Pl[gi];
        float* qp = pos_out + (size_t)(b * SS + i) * 3;
        qp[0] = c.x; qp[1] = c.y; qp[2] = c.z;
    }
    float bval = (float)batch[(size_t)b * NPTS];
    for (int i = t; i < SS; i += FPS_T) batch_out[b * SS + i] = bval;
}

// ---------------------------------------------------------------------------
// Kernel 3: radius ball query, exact K-nearest-within-R selection.
// One wave per query. nbr gets GLOBAL point ids, padded with nbr[0].
// ---------------------------------------------------------------------------
#define CAP 512

__global__ __launch_bounds__(256) void ball_kernel(const float* __restrict__ pos,
                                                   const float* __restrict__ qpos,
                                                   int* __restrict__ nbr) {
    __shared__ float cd2[4][CAP];
    __shared__ int   cidx[4][CAP];
    int t = threadIdx.x, w = t >> 6, l = t & 63;
    int qi = blockIdx.x * 4 + w;
    int b = qi >> 10;                     // S = 1024
    int bBase = b * NPTS;
    const float* P = pos + (size_t)bBase * 3;
    float qx = qpos[qi * 3 + 0], qy = qpos[qi * 3 + 1], qz = qpos[qi * 3 + 2];

    int total = 0;
    for (int n0 = 0; n0 < NPTS; n0 += 64) {
        int n = n0 + l;
        float x = P[n * 3 + 0], y = P[n * 3 + 1], z = P[n * 3 + 2];
        float dx = __fsub_rn(qx, x);
        float dy = __fsub_rn(qy, y);
        float dz = __fsub_rn(qz, z);
        float d2 = __fadd_rn(__fadd_rn(__fmul_rn(dx, dx), __fmul_rn(dy, dy)), __fmul_rn(dz, dz));
        bool in = (d2 <= 0.04f);
        unsigned long long mask = __ballot(in);
        int mypos = total + (int)__popcll(mask & ((1ull << l) - 1ull));
        if (in && mypos < CAP) { cd2[w][mypos] = d2; cidx[w][mypos] = n; }
        total += (int)__popcll(mask);
    }

    int* onbr = nbr + (size_t)qi * KK;
    if (total <= KK) {
        for (int i = l; i < KK; i += 64)
            onbr[i] = bBase + cidx[w][i < total ? i : 0];
    } else {
        int nc = total < CAP ? total : CAP;
        unsigned long long key[8];
#pragma unroll
        for (int i = 0; i < 8; i++) {
            int p = l + (i << 6);
            key[i] = (p < nc)
                   ? ((((unsigned long long)__float_as_uint(cd2[w][p])) << 12) | (unsigned)cidx[w][p])
                   : ~0ull;
        }
        unsigned long long lo = 0, hi = ((unsigned long long)0x3D23D70Bu) << 12;
        while (lo < hi) {                      // wave-uniform
            unsigned long long mid = (lo + hi) >> 1;
            int cnt = 0;
#pragma unroll
            for (int i = 0; i < 8; i++) cnt += (int)__popcll(__ballot(key[i] <= mid));
            if (cnt >= KK) hi = mid; else lo = mid + 1;
        }
        int done = 0;
#pragma unroll
        for (int i = 0; i < 8; i++) {
            bool s2 = (key[i] <= lo);
            unsigned long long mk = __ballot(s2);
            int p2 = done + (int)__popcll(mk & ((1ull << l) - 1ull));
            if (s2) onbr[p2] = bBase + (int)(key[i] & 0xFFFull);
            done += (int)__popcll(mk);
        }
    }
}

// ---------------------------------------------------------------------------
// Kernel 4: gather + 2x MFMA layers (f16 in / f32 acc) + column max.
// 256 threads = 4 waves; each wave owns 32 neighbor rows of one query.
// ---------------------------------------------------------------------------
__global__ __launch_bounds__(256) void mlp_kernel(const float* __restrict__ E,
                                                  const int* __restrict__ nbr,
                                                  const float* __restrict__ qpos,
                                                  const float* __restrict__ W1,
                                                  const float* __restrict__ b1,
                                                  const float* __restrict__ W2,
                                                  const float* __restrict__ b2,
                                                  const float* __restrict__ W3,
                                                  const float* __restrict__ b3,
                                                  float* __restrict__ xout,
                                                  int qPerBlk) {
    __shared__ __align__(16) _Float16 W2t[64 * 64];    // [n][k] swizzled
    __shared__ __align__(16) _Float16 W3t[128 * 64];   // [n][k] swizzled
    __shared__ __align__(16) _Float16 h2buf[4][32 * 64];
    __shared__ __align__(16) float csh[64];
    __shared__ float cpart[4][128];
    __shared__ float b2s[64];
    __shared__ float b3s[128];

    int t = threadIdx.x, w = t >> 6, l = t & 63;
    int lhi = l >> 4, llo = l & 15;

    for (int i = t; i < 64 * 64; i += 256) {
        int n = i >> 6, k = i & 63;
        W2t[(n << 6) | (k ^ ((n & 7) << 3))] = (_Float16)W2[k * 64 + n];
    }
    for (int i = t; i < 128 * 64; i += 256) {
        int n = i >> 6, k = i & 63;
        W3t[(n << 6) | (k ^ ((n & 7) << 3))] = (_Float16)W3[k * 128 + n];
    }
    if (t < 64) b2s[t] = b2[t];
    if (t < 128) b3s[t] = b3[t];
    __syncthreads();

    int q0 = blockIdx.x * qPerBlk;
    for (int qq = 0; qq < qPerBlk; qq++) {
        int qi = q0 + qq;
        if (t < 64) {
            float qx = qpos[qi * 3 + 0], qy = qpos[qi * 3 + 1], qz = qpos[qi * 3 + 2];
            csh[t] = b1[t] - (qx * W1[3 * 64 + t] + qy * W1[4 * 64 + t] + qz * W1[5 * 64 + t]);
        }
        __syncthreads();

        // ---- layer-1 A fragments straight from E gather
        half8 a2[2][2];
        int row0 = w * 32;
#pragma unroll
        for (int mt = 0; mt < 2; mt++) {
            int r = row0 + mt * 16 + llo;
            int nb = nbr[(size_t)qi * KK + r];
            const float* Er = E + (size_t)nb * 64;
#pragma unroll
            for (int ks = 0; ks < 2; ks++) {
                int k0 = lhi * 8 + ks * 32;
                f32x4 e0 = *(const f32x4*)(Er + k0);
                f32x4 e1 = *(const f32x4*)(Er + k0 + 4);
                f32x4 c0 = *(const f32x4*)(csh + k0);
                f32x4 c1 = *(const f32x4*)(csh + k0 + 4);
                half8 a;
#pragma unroll
                for (int e = 0; e < 4; e++) {
                    a[e]     = (_Float16)fmaxf(e0[e] + c0[e], 0.f);
                    a[4 + e] = (_Float16)fmaxf(e1[e] + c1[e], 0.f);
                }
                a2[mt][ks] = a;
            }
        }

        // ---- layer 2: [32,64] @ W2[64,64]
        f32x4 acc2[2][4];
#pragma unroll
        for (int mt = 0; mt < 2; mt++)
#pragma unroll
            for (int nt = 0; nt < 4; nt++) acc2[mt][nt] = (f32x4){0.f, 0.f, 0.f, 0.f};
#pragma unroll
        for (int ks = 0; ks < 2; ks++) {
            int k0 = lhi * 8 + ks * 32;
#pragma unroll
            for (int nt = 0; nt < 4; nt++) {
                int n = nt * 16 + llo;
                half8 bf = *(const half8*)&W2t[(n << 6) | (k0 ^ ((n & 7) << 3))];
#pragma unroll
                for (int mt = 0; mt < 2; mt++)
                    acc2[mt][nt] = __builtin_amdgcn_mfma_f32_16x16x32_f16(a2[mt][ks], bf, acc2[mt][nt], 0, 0, 0);
            }
        }

        // ---- h2 -> wave-private LDS (relu, f16, swizzled)
        _Float16* hb = h2buf[w];
#pragma unroll
        for (int mt = 0; mt < 2; mt++)
#pragma unroll
            for (int nt = 0; nt < 4; nt++)
#pragma unroll
                for (int r = 0; r < 4; r++) {
                    int lr = mt * 16 + lhi * 4 + r;
                    int n = nt * 16 + llo;
                    float v = fmaxf(acc2[mt][nt][r] + b2s[n], 0.f);
                    hb[(lr << 6) | (n ^ ((lr & 7) << 3))] = (_Float16)v;
                }

        // ---- layer 3: [32,64] @ W3[64,128]
        half8 a3[2][2];
#pragma unroll
        for (int mt = 0; mt < 2; mt++)
#pragma unroll
            for (int ks = 0; ks < 2; ks++) {
                int lr = mt * 16 + llo;
                int k0 = lhi * 8 + ks * 32;
                a3[mt][ks] = *(const half8*)&hb[(lr << 6) | (k0 ^ ((lr & 7) << 3))];
            }
        f32x4 acc3[2][8];
#pragma unroll
        for (int mt = 0; mt < 2; mt++)
#pragma unroll
            for (int nt = 0; nt < 8; nt++) acc3[mt][nt] = (f32x4){0.f, 0.f, 0.f, 0.f};
#pragma unroll
        for (int ks = 0; ks < 2; ks++) {
            int k0 = lhi * 8 + ks * 32;
#pragma unroll
            for (int nt = 0; nt < 8; nt++) {
                int n = nt * 16 + llo;
                half8 bf = *(const half8*)&W3t[(n << 6) | (k0 ^ ((n & 7) << 3))];
#pragma unroll
                for (int mt = 0; mt < 2; mt++)
                    acc3[mt][nt] = __builtin_amdgcn_mfma_f32_16x16x32_f16(a3[mt][ks], bf, acc3[mt][nt], 0, 0, 0);
            }
        }

        // ---- column max over this wave's 32 rows, then cross-wave
#pragma unroll
        for (int nt = 0; nt < 8; nt++) {
            float m = acc3[0][nt][0];
#pragma unroll
            for (int r = 1; r < 4; r++) m = fmaxf(m, acc3[0][nt][r]);
#pragma unroll
            for (int r = 0; r < 4; r++) m = fmaxf(m, acc3[1][nt][r]);
            m = fmaxf(m, __shfl_xor(m, 16));
            m = fmaxf(m, __shfl_xor(m, 32));
            if (l < 16) cpart[w][nt * 16 + l] = m;
        }
        __syncthreads();
        if (t < 128) {
            float v = fmaxf(fmaxf(cpart[0][t], cpart[1][t]), fmaxf(cpart[2][t], cpart[3][t])) + b3s[t];
            xout[(size_t)qi * 128 + t] = v;
        }
        __syncthreads();
    }
}

// ---------------------------------------------------------------------------
extern "C" void kernel_launch(void* const* d_in, const int* in_sizes, int n_in,
                              void* d_out, int out_size, void* d_ws, size_t ws_size,
                              hipStream_t stream) {
    const float* x   = (const float*)d_in[0];
    const float* pos = (const float*)d_in[1];
    const float* W1  = (const float*)d_in[2];
    const float* b1  = (const float*)d_in[3];
    const float* W2  = (const float*)d_in[4];
    const float* b2  = (const float*)d_in[5];
    const float* W3  = (const float*)d_in[6];
    const float* b3  = (const float*)d_in[7];
    const int* batch = (const int*)d_in[8];

    float* xout      = (float*)d_out;                       // [8192][128]
    float* pos_out   = xout + (size_t)BB * SS * 128;        // [8192][3]
    float* batch_out = pos_out + (size_t)BB * SS * 3;       // [8192]

    float* E  = (float*)d_ws;                               // 32768*64 f32 = 8 MB
    int* nbr  = (int*)((char*)d_ws + (size_t)32768 * 64 * 4); // 8192*128 int = 4 MB

    fps_e_kernel<<<dim3(BB + 4096), dim3(FPS_T), 0, stream>>>(pos, batch, x, W1, E, pos_out, batch_out);
    ball_kernel<<<dim3(2048), dim3(256), 0, stream>>>(pos, pos_out, nbr);
    mlp_kernel<<<dim3(2048), dim3(256), 0, stream>>>(E, nbr, pos_out, W1, b1, W2, b2, W3, b3, xout, 4);
}

// Round 2
// 725.022 us; speedup vs baseline: 1.1302x; 1.1302x over previous
//
#include <hip/hip_runtime.h>
#include <hip/hip_fp16.h>

#define BB   8
#define NPTS 4096
#define SS   1024
#define KK   128

typedef _Float16 half8 __attribute__((ext_vector_type(8)));
typedef float    f32x4 __attribute__((ext_vector_type(4)));

// ---------------------------------------------------------------------------
// Kernel 1 (fused): blocks [0,8) = FPS (one per cloud); blocks [8,...) = E.
//   E[n][c] = x[n]*W1[0:3][c] + pos[n]*W1[3:6][c]   (query-independent)
//   FPS R4: 256 threads / 4 waves (1 wave per SIMD), 16 pts/thread.
//   Rationale: loop is VALU-issue-bound on the active CUs; per-wave argmax
//   machinery and the redundant cross-wave combine scale with wave count,
//   while md-update issue per SIMD is constant. 4 waves halves the
//   duplicated work and shrinks the combine tree 7->3 nodes.
//   Local max is folded into the md-update loop (no separate fmax tree).
//   In-loop pos_out store restored (measured faster than gsel epilogue).
// ---------------------------------------------------------------------------
#define FPS_T 256
#define PPT   16

// one DPP fmax step (old preserved on disabled lanes => identity for max)
#define DPP_FMAX(CTRL)                                                                  \
    {                                                                                   \
        unsigned o = (unsigned)__builtin_amdgcn_update_dpp(                             \
            (int)__float_as_uint(m), (int)__float_as_uint(m), CTRL, 0xF, 0xF, false);   \
        m = fmaxf(m, __uint_as_float(o));                                               \
    }

__global__ __launch_bounds__(FPS_T) void fps_e_kernel(const float* __restrict__ pos,
                                                      const int* __restrict__ batch,
                                                      const float* __restrict__ x,
                                                      const float* __restrict__ W1,
                                                      float* __restrict__ E,
                                                      float* __restrict__ pos_out,
                                                      float* __restrict__ batch_out) {
    if (blockIdx.x >= BB) {
        // ---- E part: id over 32768*64, 8192 blocks x 256 threads
        int id = (blockIdx.x - BB) * FPS_T + threadIdx.x;
        int c = id & 63;
        int n = id >> 6;
        float x0 = x[n * 3 + 0], x1 = x[n * 3 + 1], x2 = x[n * 3 + 2];
        float p0 = pos[n * 3 + 0], p1 = pos[n * 3 + 1], p2 = pos[n * 3 + 2];
        float v = x0 * W1[0 * 64 + c] + x1 * W1[1 * 64 + c] + x2 * W1[2 * 64 + c]
                + p0 * W1[3 * 64 + c] + p1 * W1[4 * 64 + c] + p2 * W1[5 * 64 + c];
        E[(size_t)n * 64 + c] = v;
        return;
    }

    // ---- FPS part
    __shared__ __align__(16) float4 Pl[NPTS];                 // 64 KB point cache
    __shared__ __align__(16) unsigned long long wkey[2][4];   // parity-double-buffered

    int b = blockIdx.x;
    int t = threadIdx.x;
    int w = t >> 6, l = t & 63;
    const float* P = pos + (size_t)b * NPTS * 3;

    // stage all coords into LDS (exact copies)
    for (int i = t; i < NPTS; i += FPS_T) {
        Pl[i] = make_float4(P[i * 3 + 0], P[i * 3 + 1], P[i * 3 + 2], 0.f);
    }
    // batch is constant within a cloud: fill batch_out now
    float bval = (float)batch[(size_t)b * NPTS];
    for (int i = t; i < SS; i += FPS_T) batch_out[b * SS + i] = bval;

    // per-thread registers
    float px[PPT], py[PPT], pz[PPT], md[PPT];
    int base = t * PPT;
#pragma unroll
    for (int j = 0; j < PPT; j++) {
        px[j] = P[(base + j) * 3 + 0];
        py[j] = P[(base + j) * 3 + 1];
        pz[j] = P[(base + j) * 3 + 2];
    }
    float c0x = P[0], c0y = P[1], c0z = P[2];
    float lm = -1.f;                 // local max, folded into update loops
#pragma unroll
    for (int j = 0; j < PPT; j++) {
        float dx = __fsub_rn(px[j], c0x);
        float dy = __fsub_rn(py[j], c0y);
        float dz = __fsub_rn(pz[j], c0z);
        md[j] = __fadd_rn(__fadd_rn(__fmul_rn(dx, dx), __fmul_rn(dy, dy)), __fmul_rn(dz, dz));
        lm = fmaxf(lm, md[j]);
    }
    if (t == 0) {
        float* qp = pos_out + (size_t)(b * SS) * 3;
        qp[0] = c0x; qp[1] = c0y; qp[2] = c0z;
    }
    __syncthreads();   // Pl ready

    for (int s = 1; s < SS; s++) {
        // smallest j attaining lm (lm carried from previous update loop)
        int jsel = 0x7FFFFFFF;
#pragma unroll
        for (int j = PPT - 1; j >= 0; j--)
            if (md[j] == lm) jsel = base + j;

        // ---- wave max via f32 DPP
        float m = lm;
        DPP_FMAX(0x111)   // row_shr:1
        DPP_FMAX(0x112)   // row_shr:2
        DPP_FMAX(0x114)   // row_shr:4
        DPP_FMAX(0x118)   // row_shr:8
        DPP_FMAX(0x142)   // row_bcast:15
        DPP_FMAX(0x143)   // row_bcast:31
        float wm = __uint_as_float((unsigned)__builtin_amdgcn_readlane(__float_as_uint(m), 63));

        // ---- first lane attaining wm = smallest index (lanes ordered by base)
        unsigned long long mask = __ballot(lm == wm);
        int L = __ffsll((long long)mask) - 1;
        int si = __builtin_amdgcn_readlane(jsel, L);          // wave's argmax index (uniform)

        if (l == 0)
            wkey[s & 1][w] = (((unsigned long long)__float_as_uint(wm)) << 32) | (~(unsigned)si);
        __syncthreads();

        // ---- cross-wave combine (uniform broadcast reads; max key = max d2, tie -> min idx)
        const unsigned long long* wk = wkey[s & 1];
        unsigned long long g0 = wk[0] > wk[1] ? wk[0] : wk[1];
        unsigned long long g1 = wk[2] > wk[3] ? wk[2] : wk[3];
        unsigned long long g = g0 > g1 ? g0 : g1;
        int gi = (int)(~(unsigned)g);

        float4 c = Pl[gi];                      // LDS broadcast
        if (t == 0) {
            float* qp = pos_out + (size_t)(b * SS + s) * 3;
            qp[0] = c.x; qp[1] = c.y; qp[2] = c.z;
        }
        float nlm = -1.f;
#pragma unroll
        for (int j = 0; j < PPT; j++) {
            float dx = __fsub_rn(px[j], c.x);
            float dy = __fsub_rn(py[j], c.y);
            float dz = __fsub_rn(pz[j], c.z);
            float d2 = __fadd_rn(__fadd_rn(__fmul_rn(dx, dx), __fmul_rn(dy, dy)), __fmul_rn(dz, dz));
            md[j] = fminf(md[j], d2);
            nlm = fmaxf(nlm, md[j]);
        }
        lm = nlm;
    }
}

// ---------------------------------------------------------------------------
// Kernel 3: radius ball query, exact K-nearest-within-R selection.
// One wave per query. nbr gets GLOBAL point ids, padded with nbr[0].
// ---------------------------------------------------------------------------
#define CAP 512

__global__ __launch_bounds__(256) void ball_kernel(const float* __restrict__ pos,
                                                   const float* __restrict__ qpos,
                                                   int* __restrict__ nbr) {
    __shared__ float cd2[4][CAP];
    __shared__ int   cidx[4][CAP];
    int t = threadIdx.x, w = t >> 6, l = t & 63;
    int qi = blockIdx.x * 4 + w;
    int b = qi >> 10;                     // S = 1024
    int bBase = b * NPTS;
    const float* P = pos + (size_t)bBase * 3;
    float qx = qpos[qi * 3 + 0], qy = qpos[qi * 3 + 1], qz = qpos[qi * 3 + 2];

    int total = 0;
    for (int n0 = 0; n0 < NPTS; n0 += 64) {
        int n = n0 + l;
        float x = P[n * 3 + 0], y = P[n * 3 + 1], z = P[n * 3 + 2];
        float dx = __fsub_rn(qx, x);
        float dy = __fsub_rn(qy, y);
        float dz = __fsub_rn(qz, z);
        float d2 = __fadd_rn(__fadd_rn(__fmul_rn(dx, dx), __fmul_rn(dy, dy)), __fmul_rn(dz, dz));
        bool in = (d2 <= 0.04f);
        unsigned long long mask = __ballot(in);
        int mypos = total + (int)__popcll(mask & ((1ull << l) - 1ull));
        if (in && mypos < CAP) { cd2[w][mypos] = d2; cidx[w][mypos] = n; }
        total += (int)__popcll(mask);
    }

    int* onbr = nbr + (size_t)qi * KK;
    if (total <= KK) {
        for (int i = l; i < KK; i += 64)
            onbr[i] = bBase + cidx[w][i < total ? i : 0];
    } else {
        int nc = total < CAP ? total : CAP;
        unsigned long long key[8];
#pragma unroll
        for (int i = 0; i < 8; i++) {
            int p = l + (i << 6);
            key[i] = (p < nc)
                   ? ((((unsigned long long)__float_as_uint(cd2[w][p])) << 12) | (unsigned)cidx[w][p])
                   : ~0ull;
        }
        unsigned long long lo = 0, hi = ((unsigned long long)0x3D23D70Bu) << 12;
        while (lo < hi) {                      // wave-uniform
            unsigned long long mid = (lo + hi) >> 1;
            int cnt = 0;
#pragma unroll
            for (int i = 0; i < 8; i++) cnt += (int)__popcll(__ballot(key[i] <= mid));
            if (cnt >= KK) hi = mid; else lo = mid + 1;
        }
        int done = 0;
#pragma unroll
        for (int i = 0; i < 8; i++) {
            bool s2 = (key[i] <= lo);
            unsigned long long mk = __ballot(s2);
            int p2 = done + (int)__popcll(mk & ((1ull << l) - 1ull));
            if (s2) onbr[p2] = bBase + (int)(key[i] & 0xFFFull);
            done += (int)__popcll(mk);
        }
    }
}

// ---------------------------------------------------------------------------
// Kernel 4: gather + 2x MFMA layers (f16 in / f32 acc) + column max.
// 256 threads = 4 waves; each wave owns 32 neighbor rows of one query.
// ---------------------------------------------------------------------------
__global__ __launch_bounds__(256) void mlp_kernel(const float* __restrict__ E,
                                                  const int* __restrict__ nbr,
                                                  const float* __restrict__ qpos,
                                                  const float* __restrict__ W1,
                                                  const float* __restrict__ b1,
                                                  const float* __restrict__ W2,
                                                  const float* __restrict__ b2,
                                                  const float* __restrict__ W3,
                                                  const float* __restrict__ b3,
                                                  float* __restrict__ xout,
                                                  int qPerBlk) {
    __shared__ __align__(16) _Float16 W2t[64 * 64];    // [n][k] swizzled
    __shared__ __align__(16) _Float16 W3t[128 * 64];   // [n][k] swizzled
    __shared__ __align__(16) _Float16 h2buf[4][32 * 64];
    __shared__ __align__(16) float csh[64];
    __shared__ float cpart[4][128];
    __shared__ float b2s[64];
    __shared__ float b3s[128];

    int t = threadIdx.x, w = t >> 6, l = t & 63;
    int lhi = l >> 4, llo = l & 15;

    for (int i = t; i < 64 * 64; i += 256) {
        int n = i >> 6, k = i & 63;
        W2t[(n << 6) | (k ^ ((n & 7) << 3))] = (_Float16)W2[k * 64 + n];
    }
    for (int i = t; i < 128 * 64; i += 256) {
        int n = i >> 6, k = i & 63;
        W3t[(n << 6) | (k ^ ((n & 7) << 3))] = (_Float16)W3[k * 128 + n];
    }
    if (t < 64) b2s[t] = b2[t];
    if (t < 128) b3s[t] = b3[t];
    __syncthreads();

    int q0 = blockIdx.x * qPerBlk;
    for (int qq = 0; qq < qPerBlk; qq++) {
        int qi = q0 + qq;
        if (t < 64) {
            float qx = qpos[qi * 3 + 0], qy = qpos[qi * 3 + 1], qz = qpos[qi * 3 + 2];
            csh[t] = b1[t] - (qx * W1[3 * 64 + t] + qy * W1[4 * 64 + t] + qz * W1[5 * 64 + t]);
        }
        __syncthreads();

        // ---- layer-1 A fragments straight from E gather
        half8 a2[2][2];
        int row0 = w * 32;
#pragma unroll
        for (int mt = 0; mt < 2; mt++) {
            int r = row0 + mt * 16 + llo;
            int nb = nbr[(size_t)qi * KK + r];
            const float* Er = E + (size_t)nb * 64;
#pragma unroll
            for (int ks = 0; ks < 2; ks++) {
                int k0 = lhi * 8 + ks * 32;
                f32x4 e0 = *(const f32x4*)(Er + k0);
                f32x4 e1 = *(const f32x4*)(Er + k0 + 4);
                f32x4 c0 = *(const f32x4*)(csh + k0);
                f32x4 c1 = *(const f32x4*)(csh + k0 + 4);
                half8 a;
#pragma unroll
                for (int e = 0; e < 4; e++) {
                    a[e]     = (_Float16)fmaxf(e0[e] + c0[e], 0.f);
                    a[4 + e] = (_Float16)fmaxf(e1[e] + c1[e], 0.f);
                }
                a2[mt][ks] = a;
            }
        }

        // ---- layer 2: [32,64] @ W2[64,64]
        f32x4 acc2[2][4];
#pragma unroll
        for (int mt = 0; mt < 2; mt++)
#pragma unroll
            for (int nt = 0; nt < 4; nt++) acc2[mt][nt] = (f32x4){0.f, 0.f, 0.f, 0.f};
#pragma unroll
        for (int ks = 0; ks < 2; ks++) {
            int k0 = lhi * 8 + ks * 32;
#pragma unroll
            for (int nt = 0; nt < 4; nt++) {
                int n = nt * 16 + llo;
                half8 bf = *(const half8*)&W2t[(n << 6) | (k0 ^ ((n & 7) << 3))];
#pragma unroll
                for (int mt = 0; mt < 2; mt++)
                    acc2[mt][nt] = __builtin_amdgcn_mfma_f32_16x16x32_f16(a2[mt][ks], bf, acc2[mt][nt], 0, 0, 0);
            }
        }

        // ---- h2 -> wave-private LDS (relu, f16, swizzled)
        _Float16* hb = h2buf[w];
#pragma unroll
        for (int mt = 0; mt < 2; mt++)
#pragma unroll
            for (int nt = 0; nt < 4; nt++)
#pragma unroll
                for (int r = 0; r < 4; r++) {
                    int lr = mt * 16 + lhi * 4 + r;
                    int n = nt * 16 + llo;
                    float v = fmaxf(acc2[mt][nt][r] + b2s[n], 0.f);
                    hb[(lr << 6) | (n ^ ((lr & 7) << 3))] = (_Float16)v;
                }

        // ---- layer 3: [32,64] @ W3[64,128]
        half8 a3[2][2];
#pragma unroll
        for (int mt = 0; mt < 2; mt++)
#pragma unroll
            for (int ks = 0; ks < 2; ks++) {
                int lr = mt * 16 + llo;
                int k0 = lhi * 8 + ks * 32;
                a3[mt][ks] = *(const half8*)&hb[(lr << 6) | (k0 ^ ((lr & 7) << 3))];
            }
        f32x4 acc3[2][8];
#pragma unroll
        for (int mt = 0; mt < 2; mt++)
#pragma unroll
            for (int nt = 0; nt < 8; nt++) acc3[mt][nt] = (f32x4){0.f, 0.f, 0.f, 0.f};
#pragma unroll
        for (int ks = 0; ks < 2; ks++) {
            int k0 = lhi * 8 + ks * 32;
#pragma unroll
            for (int nt = 0; nt < 8; nt++) {
                int n = nt * 16 + llo;
                half8 bf = *(const half8*)&W3t[(n << 6) | (k0 ^ ((n & 7) << 3))];
#pragma unroll
                for (int mt = 0; mt < 2; mt++)
                    acc3[mt][nt] = __builtin_amdgcn_mfma_f32_16x16x32_f16(a3[mt][ks], bf, acc3[mt][nt], 0, 0, 0);
            }
        }

        // ---- column max over this wave's 32 rows, then cross-wave
#pragma unroll
        for (int nt = 0; nt < 8; nt++) {
            float m = acc3[0][nt][0];
#pragma unroll
            for (int r = 1; r < 4; r++) m = fmaxf(m, acc3[0][nt][r]);
#pragma unroll
            for (int r = 0; r < 4; r++) m = fmaxf(m, acc3[1][nt][r]);
            m = fmaxf(m, __shfl_xor(m, 16));
            m = fmaxf(m, __shfl_xor(m, 32));
            if (l < 16) cpart[w][nt * 16 + l] = m;
        }
        __syncthreads();
        if (t < 128) {
            float v = fmaxf(fmaxf(cpart[0][t], cpart[1][t]), fmaxf(cpart[2][t], cpart[3][t])) + b3s[t];
            xout[(size_t)qi * 128 + t] = v;
        }
        __syncthreads();
    }
}

// ---------------------------------------------------------------------------
extern "C" void kernel_launch(void* const* d_in, const int* in_sizes, int n_in,
                              void* d_out, int out_size, void* d_ws, size_t ws_size,
                              hipStream_t stream) {
    const float* x   = (const float*)d_in[0];
    const float* pos = (const float*)d_in[1];
    const float* W1  = (const float*)d_in[2];
    const float* b1  = (const float*)d_in[3];
    const float* W2  = (const float*)d_in[4];
    const float* b2  = (const float*)d_in[5];
    const float* W3  = (const float*)d_in[6];
    const float* b3  = (const float*)d_in[7];
    const int* batch = (const int*)d_in[8];

    float* xout      = (float*)d_out;                       // [8192][128]
    float* pos_out   = xout + (size_t)BB * SS * 128;        // [8192][3]
    float* batch_out = pos_out + (size_t)BB * SS * 3;       // [8192]

    float* E  = (float*)d_ws;                               // 32768*64 f32 = 8 MB
    int* nbr  = (int*)((char*)d_ws + (size_t)32768 * 64 * 4); // 8192*128 int = 4 MB

    fps_e_kernel<<<dim3(BB + 8192), dim3(FPS_T), 0, stream>>>(pos, batch, x, W1, E, pos_out, batch_out);
    ball_kernel<<<dim3(2048), dim3(256), 0, stream>>>(pos, pos_out, nbr);
    mlp_kernel<<<dim3(2048), dim3(256), 0, stream>>>(E, nbr, pos_out, W1, b1, W2, b2, W3, b3, xout, 4);
}